// Round 3
// baseline (10812.259 us; speedup 1.0000x reference)
//
#include <hip/hip_runtime.h>
#include <math.h>

// DCGRU encoder — fused per-(layer,batch) persistent blocks, LDS-only
// intermediates. B=16 T=32 N=128 D=H=128, K=2 (M=3), L=2, 1 support.
//
// R2 post-mortem: 32-block fusion with D1/D2/u in global was 2x WORSE
// (218us/stage): weights+D round trips thrashed L2 (FETCH 1.15GB) and
// 32 blocks can't hide the latency; scattered 2-B global stores drained
// at every barrier. Fix: NO intermediate ever leaves the CU.
//  - Each diffusion hop dual-writes its output to LDS: f-major (B-operand
//    of next hop) + row-major (A-operand of weight GEMM, ds_read_b128).
//    Intra-hop __syncthreads + register-captured Chebyshev x0 lets two
//    32KB tiles suffice.
//  - GEMM chunks consumed right after production: acc_g/acc_c accumulate
//    across chunks in registers; u (update gate) lives in registers
//    (gates wave == candidate wave by tiling construction).
//  - Remaining global traffic per stage/block: weight frags 590KB (read,
//    shared across blocks -> L2), x 64KB, out/seqs 64KB write.
// Grid: 32 blocks x 1024 thr (1 block/CU, 128KB LDS), 33 grid barriers.

typedef __attribute__((ext_vector_type(8))) short bf16x8;
typedef __attribute__((ext_vector_type(4))) float f32x4;

namespace {
constexpr int GD = 32, NTHR = 1024;
}

__device__ __forceinline__ unsigned short f2bf(float x) {
  unsigned u = __float_as_uint(x);
  u += 0x7fff + ((u >> 16) & 1);  // RNE
  return (unsigned short)(u >> 16);
}
__device__ __forceinline__ float bf2f(unsigned hw) {
  return __uint_as_float(hw << 16);
}
__device__ __forceinline__ unsigned pk2(float a, float b) {
  return (unsigned)f2bf(a) | ((unsigned)f2bf(b) << 16);
}
// swizzled halfword index into a [128][128] bf16 LDS tile (row stride 256B)
__device__ __forceinline__ int BIdx(int r, int c) {
  return (r << 7) + (c ^ ((r & 7) << 3));
}
// swizzled word index into the [128][128] f32 h tile
__device__ __forceinline__ int HsIdx(int n, int f) {
  return (n << 7) + (f ^ (n & 31));
}

// sense-reversing grid barrier (verified across XCDs in earlier rounds)
__device__ __forceinline__ void grid_barrier(unsigned* bar) {
  __syncthreads();
  if (threadIdx.x == 0) {
    unsigned* cnt = bar;
    unsigned* gen = bar + 32;
    unsigned g = __hip_atomic_load(gen, __ATOMIC_RELAXED, __HIP_MEMORY_SCOPE_AGENT);
    unsigned a = __hip_atomic_fetch_add(cnt, 1u, __ATOMIC_ACQ_REL, __HIP_MEMORY_SCOPE_AGENT);
    if (a == (unsigned)(GD - 1)) {
      __hip_atomic_store(cnt, 0u, __ATOMIC_RELAXED, __HIP_MEMORY_SCOPE_AGENT);
      __hip_atomic_fetch_add(gen, 1u, __ATOMIC_ACQ_REL, __HIP_MEMORY_SCOPE_AGENT);
    } else {
      while (__hip_atomic_load(gen, __ATOMIC_ACQUIRE, __HIP_MEMORY_SCOPE_AGENT) == g) {
        __builtin_amdgcn_s_sleep(1);
      }
    }
  }
  __syncthreads();
}

// One diffusion hop (16 waves, 32m x 32f tiles): out = S @ Bt
// (Bt f-major [f][n]); optional Chebyshev out = 2*out - ct(regs);
// optional capture of Bt values at the output slots (next hop's x0);
// optional f-major write (next hop's B); row-major write always
// (weight-GEMM A-chunk). ISYNC when a written tile is also read here.
template <bool HASCT, bool CAP, bool FMAJ, bool ISYNC>
__device__ __forceinline__ void diff_hop(
    const unsigned short* __restrict__ Sb, const unsigned short* Bt,
    unsigned short* fmaj, unsigned short* rmaj, uint2 (*ct)[2], uint2 (*cap)[2],
    int w, int lane, int quad, int l16) {
  const int mtg = w >> 2, ftg = w & 3;
  f32x4 acc[2][2];
#pragma unroll
  for (int mi = 0; mi < 2; ++mi)
#pragma unroll
    for (int fi = 0; fi < 2; ++fi) acc[mi][fi] = (f32x4){0.f, 0.f, 0.f, 0.f};
#pragma unroll
  for (int ks = 0; ks < 4; ++ks) {
    bf16x8 a[2], bb[2];
#pragma unroll
    for (int mi = 0; mi < 2; ++mi)
      a[mi] = *(const bf16x8*)(Sb + (((mtg * 2 + mi) * 4 + ks) * 64 + lane) * 8);
#pragma unroll
    for (int fi = 0; fi < 2; ++fi)
      bb[fi] = *(const bf16x8*)(Bt + BIdx((ftg * 2 + fi) * 16 + l16, ks * 32 + quad * 8));
#pragma unroll
    for (int mi = 0; mi < 2; ++mi)
#pragma unroll
      for (int fi = 0; fi < 2; ++fi)
        acc[mi][fi] =
            __builtin_amdgcn_mfma_f32_16x16x32_bf16(a[mi], bb[fi], acc[mi][fi], 0, 0, 0);
  }
  float v[2][2][4];
#pragma unroll
  for (int mi = 0; mi < 2; ++mi)
#pragma unroll
    for (int fi = 0; fi < 2; ++fi) {
      const int f = (ftg * 2 + fi) * 16 + l16;
      const int m0 = (mtg * 2 + mi) * 16 + quad * 4;
#pragma unroll
      for (int r = 0; r < 4; ++r) v[mi][fi][r] = acc[mi][fi][r];
      if (HASCT) {
        const uint2 cv = ct[mi][fi];
        v[mi][fi][0] = 2.f * v[mi][fi][0] - bf2f(cv.x & 0xffffu);
        v[mi][fi][1] = 2.f * v[mi][fi][1] - bf2f(cv.x >> 16);
        v[mi][fi][2] = 2.f * v[mi][fi][2] - bf2f(cv.y & 0xffffu);
        v[mi][fi][3] = 2.f * v[mi][fi][3] - bf2f(cv.y >> 16);
      }
      if (CAP) cap[mi][fi] = *(const uint2*)(Bt + BIdx(f, m0));
      if (FMAJ)
        *(uint2*)(fmaj + BIdx(f, m0)) =
            make_uint2(pk2(v[mi][fi][0], v[mi][fi][1]), pk2(v[mi][fi][2], v[mi][fi][3]));
    }
  if (ISYNC) __syncthreads();
#pragma unroll
  for (int mi = 0; mi < 2; ++mi)
#pragma unroll
    for (int fi = 0; fi < 2; ++fi) {
      const int f = (ftg * 2 + fi) * 16 + l16;
      const int m0 = (mtg * 2 + mi) * 16 + quad * 4;
#pragma unroll
      for (int r = 0; r < 4; ++r) rmaj[BIdx(m0 + r, f)] = f2bf(v[mi][fi][r]);
    }
}

// A-fragment loaders (16x16x32 A-operand: lane l16 = row m, quad = k-chunk)
__device__ __forceinline__ bf16x8 afrag_rm(const unsigned short* T, int m, int k0) {
  return *(const bf16x8*)(T + BIdx(m, k0));
}
__device__ __forceinline__ bf16x8 afrag_G(const float* __restrict__ g, int m, int k0) {
  const float4 v0 = *(const float4*)(g + m * 128 + k0);
  const float4 v1 = *(const float4*)(g + m * 128 + k0 + 4);
  bf16x8 a;
  a[0] = (short)f2bf(v0.x); a[1] = (short)f2bf(v0.y);
  a[2] = (short)f2bf(v0.z); a[3] = (short)f2bf(v0.w);
  a[4] = (short)f2bf(v1.x); a[5] = (short)f2bf(v1.y);
  a[6] = (short)f2bf(v1.z); a[7] = (short)f2bf(v1.w);
  return a;
}
__device__ __forceinline__ bf16x8 afrag_Hs(const float* Hsp, int m, int k0) {
  bf16x8 a;
#pragma unroll
  for (int j = 0; j < 8; ++j) a[j] = (short)f2bf(Hsp[HsIdx(m, k0 + j)]);
  return a;
}

// weight-GEMM accumulate for one k-chunk c (gates: 8 o-frags = r+u halves)
__device__ __forceinline__ void gemm_gates(const bf16x8 (&af)[4],
    const unsigned short* __restrict__ WgL, int c, int ow, int lane, f32x4 (&accg)[8]) {
#pragma unroll
  for (int ks = 0; ks < 4; ++ks)
#pragma unroll
    for (int of = 0; of < 8; ++of) {
      const int ot = (of < 4) ? (ow * 4 + of) : (4 + ow * 4 + of);  // of>=4 -> 8+ow*4+(of-4)
      const bf16x8 bb =
          *(const bf16x8*)(WgL + ((long)(ot * 24 + c * 4 + ks)) * 512 + (long)lane * 8);
      accg[of] = __builtin_amdgcn_mfma_f32_16x16x32_bf16(af[ks], bb, accg[of], 0, 0, 0);
    }
}
__device__ __forceinline__ void gemm_cand(const bf16x8 (&af)[4],
    const unsigned short* __restrict__ WcL, int c, int ow, int lane, f32x4 (&accc)[4]) {
#pragma unroll
  for (int ks = 0; ks < 4; ++ks)
#pragma unroll
    for (int of = 0; of < 4; ++of) {
      const int ot = ow * 4 + of;
      const bf16x8 bb =
          *(const bf16x8*)(WcL + ((long)(ot * 24 + c * 4 + ks)) * 512 + (long)lane * 8);
      accc[of] = __builtin_amdgcn_mfma_f32_16x16x32_bf16(af[ks], bb, accc[of], 0, 0, 0);
    }
}

__global__ void __launch_bounds__(NTHR, 4) dcgru(
    const float* __restrict__ inputs, const float* __restrict__ init_h,
    const float* __restrict__ sup,
    const float* __restrict__ Wg0, const float* __restrict__ bg0,
    const float* __restrict__ Wc0, const float* __restrict__ bc0,
    const float* __restrict__ Wg1, const float* __restrict__ bg1,
    const float* __restrict__ Wc1, const float* __restrict__ bc1,
    float* __restrict__ out, void* __restrict__ wsv) {
  __shared__ float Hs[16384];           // 64 KB h state (f32, swizzled)
  __shared__ unsigned short T1[16384];  // 32 KB work tile
  __shared__ unsigned short T2[16384];  // 32 KB work tile

  unsigned* bar = (unsigned*)wsv;
  float* seqs = (float*)wsv + 64;                           // [2][16][128][128]
  unsigned short* Sfr = (unsigned short*)(seqs + 524288);   // [32][8][4][64][8]
  unsigned short* Wbg = Sfr + 524288;                       // [2][16][24][64][8]
  unsigned short* Wbc = Wbg + 393216;                       // [2][8][24][64][8]

  const int tid = threadIdx.x, bid = blockIdx.x;
  const int gtid = bid * NTHR + tid, gstride = GD * NTHR;
  const int lane = tid & 63, w = tid >> 6, quad = lane >> 4, l16 = lane & 15;
  const int layer = bid >> 4, b = bid & 15;
  const int mw = w >> 1, ow = w & 1;  // GEMM tiling: 16m x (64r+64u | 64c)

  // ---- prep: h -> LDS; S/W fragment pre-arrangement (bf16) ----
  for (int i = tid; i < 16384; i += NTHR)
    Hs[HsIdx(i >> 7, i & 127)] = init_h[(long)(layer * 16 + b) * 16384 + i];
  for (int idx = gtid; idx < 65536; idx += gstride) {  // S frags
    const int tt = idx >> 11, mt = (idx >> 8) & 7, ks = (idx >> 6) & 3, ln = idx & 63;
    const int m = mt * 16 + (ln & 15), k0 = ks * 32 + (ln >> 4) * 8;
    const float* src = sup + (long)tt * 16384 + m * 128 + k0;
    bf16x8 v;
#pragma unroll
    for (int j = 0; j < 8; j++) v[j] = (short)f2bf(src[j]);
    *(bf16x8*)(Sfr + (long)idx * 8) = v;
  }
  for (int idx = gtid; idx < 49152; idx += gstride) {  // Wg frags (2x16x24x64)
    const int l = idx / 24576;
    int rem = idx - l * 24576;
    const int ot = rem / 1536; rem -= ot * 1536;
    const int ks = rem >> 6, ln = rem & 63;
    const int o = ot * 16 + (ln & 15);
    const float* W = l ? Wg1 : Wg0;
    bf16x8 v;
#pragma unroll
    for (int j = 0; j < 8; j++) {
      const int kk = ks * 32 + (ln >> 4) * 8 + j;
      const int mm = kk >> 8, d = kk & 255;  // row reorder (d*3+mm) -> k
      v[j] = (short)f2bf(W[(d * 3 + mm) * 256 + o]);
    }
    *(bf16x8*)(Wbg + (long)idx * 8) = v;
  }
  for (int idx = gtid; idx < 24576; idx += gstride) {  // Wc frags (2x8x24x64)
    const int l = idx / 12288;
    int rem = idx - l * 12288;
    const int ot = rem / 1536; rem -= ot * 1536;
    const int ks = rem >> 6, ln = rem & 63;
    const int o = ot * 16 + (ln & 15);
    const float* W = l ? Wc1 : Wc0;
    bf16x8 v;
#pragma unroll
    for (int j = 0; j < 8; j++) {
      const int kk = ks * 32 + (ln >> 4) * 8 + j;
      const int mm = kk >> 8, d = kk & 255;
      v[j] = (short)f2bf(W[(d * 3 + mm) * 128 + o]);
    }
    *(bf16x8*)(Wbc + (long)idx * 8) = v;
  }
  grid_barrier(bar);

  const float* bgL = layer ? bg1 : bg0;
  const float* bcL = layer ? bc1 : bc0;
  const unsigned short* WgL = Wbg + (long)layer * 16 * 24 * 512;
  const unsigned short* WcL = Wbc + (long)layer * 8 * 24 * 512;

  // ---- main pipelined loop: stage s, layer0 does t=s, layer1 does t=s-1 ----
  for (int s = 0; s < 33; ++s) {
    const int t = layer ? (s - 1) : s;
    const bool act = layer ? (s >= 1) : (s < 32);
    if (act) {
      const float* xsrc = (layer == 0)
          ? inputs + (long)(b * 32 + t) * 16384
          : seqs + (long)(t & 1) * 262144 + (long)b * 16384;
      const unsigned short* Sb = Sfr + (long)t * 16384;
      const int m = mw * 16 + l16;

      f32x4 accg[8], accc[4];
#pragma unroll
      for (int of = 0; of < 8; ++of) accg[of] = (f32x4){0.f, 0.f, 0.f, 0.f};
#pragma unroll
      for (int of = 0; of < 4; ++of) accc[of] = (f32x4){0.f, 0.f, 0.f, 0.f};
      uint2 cap[2][2];

      // ---- phase A: x | D1x | D2x (both GEMMs) ----
      // A1: build xT -> T1
#pragma unroll
      for (int it = 0; it < 8; ++it) {
        const int f = it * 16 + w, n2 = lane << 1;
        const float v0 = xsrc[n2 * 128 + f], v1 = xsrc[(n2 + 1) * 128 + f];
        *(unsigned*)(T1 + BIdx(f, n2)) = pk2(v0, v1);
      }
      __syncthreads();
      // A2: D1x = S@T1; fmaj->T2, rmaj->T1 (own B: isync), capture x
      diff_hop<false, true, true, true>(Sb, T1, T2, T1, nullptr, cap, w, lane, quad, l16);
      __syncthreads();
      // A3: GEMM c0 (x from global) + c2 (D1x rmaj T1)
      {
        bf16x8 af[4];
#pragma unroll
        for (int ks = 0; ks < 4; ++ks) af[ks] = afrag_G(xsrc, m, ks * 32 + quad * 8);
        gemm_gates(af, WgL, 0, ow, lane, accg);
        gemm_cand(af, WcL, 0, ow, lane, accc);
#pragma unroll
        for (int ks = 0; ks < 4; ++ks) af[ks] = afrag_rm(T1, m, ks * 32 + quad * 8);
        gemm_gates(af, WgL, 2, ow, lane, accg);
        gemm_cand(af, WcL, 2, ow, lane, accc);
      }
      __syncthreads();
      // A4: D2x = 2 S@T2 - x(regs); rmaj->T2 (own B: isync)
      diff_hop<true, false, false, true>(Sb, T2, nullptr, T2, cap, nullptr, w, lane, quad, l16);
      __syncthreads();
      // A5: GEMM c4 (D2x rmaj T2)
      {
        bf16x8 af[4];
#pragma unroll
        for (int ks = 0; ks < 4; ++ks) af[ks] = afrag_rm(T2, m, ks * 32 + quad * 8);
        gemm_gates(af, WgL, 4, ow, lane, accg);
        gemm_cand(af, WcL, 4, ow, lane, accc);
      }
      __syncthreads();

      // ---- phase B: h | D1h | D2h (gates GEMM only) ----
      // B1: build hT -> T1
#pragma unroll
      for (int it = 0; it < 8; ++it) {
        const int f = it * 16 + w, n2 = lane << 1;
        const float v0 = Hs[HsIdx(n2, f)], v1 = Hs[HsIdx(n2 + 1, f)];
        *(unsigned*)(T1 + BIdx(f, n2)) = pk2(v0, v1);
      }
      __syncthreads();
      // B2: D1h; fmaj->T2, rmaj->T1, capture h
      diff_hop<false, true, true, true>(Sb, T1, T2, T1, nullptr, cap, w, lane, quad, l16);
      __syncthreads();
      // B3: GEMM c1 (h from Hs) + c3 (D1h rmaj T1)
      {
        bf16x8 af[4];
#pragma unroll
        for (int ks = 0; ks < 4; ++ks) af[ks] = afrag_Hs(Hs, m, ks * 32 + quad * 8);
        gemm_gates(af, WgL, 1, ow, lane, accg);
#pragma unroll
        for (int ks = 0; ks < 4; ++ks) af[ks] = afrag_rm(T1, m, ks * 32 + quad * 8);
        gemm_gates(af, WgL, 3, ow, lane, accg);
      }
      __syncthreads();
      // B4: D2h = 2 S@T2 - h(regs); rmaj->T2 (own B: isync)
      diff_hop<true, false, false, true>(Sb, T2, nullptr, T2, cap, nullptr, w, lane, quad, l16);
      __syncthreads();
      // B5: GEMM c5 (D2h rmaj T2)
      {
        bf16x8 af[4];
#pragma unroll
        for (int ks = 0; ks < 4; ++ks) af[ks] = afrag_rm(T2, m, ks * 32 + quad * 8);
        gemm_gates(af, WgL, 5, ow, lane, accg);
      }
      __syncthreads();

      // ---- gates epilogue: r -> rh (fmaj T1 + rmaj T2); u -> registers ----
#pragma unroll
      for (int of = 0; of < 4; ++of) {
        const int o = ow * 64 + of * 16 + l16;
        const float bias = bgL[o];
        const int m0 = mw * 16 + quad * 4;
        float rh[4];
#pragma unroll
        for (int r = 0; r < 4; ++r) {
          const float g = 1.f / (1.f + __expf(-(accg[of][r] + bias)));
          rh[r] = g * Hs[HsIdx(m0 + r, o)];
        }
        *(uint2*)(T1 + BIdx(o, m0)) = make_uint2(pk2(rh[0], rh[1]), pk2(rh[2], rh[3]));
#pragma unroll
        for (int r = 0; r < 4; ++r) T2[BIdx(m0 + r, o)] = f2bf(rh[r]);
      }
#pragma unroll
      for (int of = 4; of < 8; ++of) {
        const int o = 128 + ow * 64 + (of - 4) * 16 + l16;
        const float bias = bgL[o];
#pragma unroll
        for (int r = 0; r < 4; ++r)
          accg[of][r] = 1.f / (1.f + __expf(-(accg[of][r] + bias)));
      }
      __syncthreads();

      // ---- phase C: rh | D1rh | D2rh (candidate GEMM) ----
      // C2a: GEMM c1 cand (rh rmaj T2)
      {
        bf16x8 af[4];
#pragma unroll
        for (int ks = 0; ks < 4; ++ks) af[ks] = afrag_rm(T2, m, ks * 32 + quad * 8);
        gemm_cand(af, WcL, 1, ow, lane, accc);
      }
      __syncthreads();
      // C1: D1rh = S@T1(rhT); fmaj->T2, rmaj->T1 (own B: isync), capture rh
      diff_hop<false, true, true, true>(Sb, T1, T2, T1, nullptr, cap, w, lane, quad, l16);
      __syncthreads();
      // C2b: GEMM c3 cand (D1rh rmaj T1)
      {
        bf16x8 af[4];
#pragma unroll
        for (int ks = 0; ks < 4; ++ks) af[ks] = afrag_rm(T1, m, ks * 32 + quad * 8);
        gemm_cand(af, WcL, 3, ow, lane, accc);
      }
      __syncthreads();
      // C3: D2rh = 2 S@T2 - rh(regs); rmaj->T1 (different tile: no isync)
      diff_hop<true, false, false, false>(Sb, T2, nullptr, T1, cap, nullptr, w, lane, quad, l16);
      __syncthreads();
      // C4: GEMM c5 cand (D2rh rmaj T1)
      {
        bf16x8 af[4];
#pragma unroll
        for (int ks = 0; ks < 4; ++ks) af[ks] = afrag_rm(T1, m, ks * 32 + quad * 8);
        gemm_cand(af, WcL, 5, ow, lane, accc);
      }

      // ---- final epilogue: c = tanh(acc_c+bc); h' = u*h + (1-u)*c ----
#pragma unroll
      for (int of = 0; of < 4; ++of) {
        const int o = ow * 64 + of * 16 + l16;
        const float bias = bcL[o];
#pragma unroll
        for (int r = 0; r < 4; ++r) {
          const int mm = mw * 16 + quad * 4 + r;
          const float cv = tanhf(accc[of][r] + bias);
          const float uv = accg[4 + of][r];
          const float hv = Hs[HsIdx(mm, o)];
          const float hn = uv * hv + (1.f - uv) * cv;
          Hs[HsIdx(mm, o)] = hn;
          const long base = (long)(b * 128 + mm) * 128 + o;
          if (layer == 0) {
            seqs[(long)(s & 1) * 262144 + base] = hn;
            if (t == 31) out[base] = hn;
          } else {
            out[524288 + (long)t * 262144 + base] = hn;
            if (t == 31) out[262144 + base] = hn;
          }
        }
      }
    }  // act
    grid_barrier(bar);
  }
}

extern "C" void kernel_launch(void* const* d_in, const int* in_sizes, int n_in,
                              void* d_out, int out_size, void* d_ws, size_t ws_size,
                              hipStream_t stream) {
  const float* inputs = (const float*)d_in[0];
  const float* init_h = (const float*)d_in[1];
  const float* sup    = (const float*)d_in[2];
  const float* Wg0 = (const float*)d_in[3];
  const float* bg0 = (const float*)d_in[4];
  const float* Wc0 = (const float*)d_in[5];
  const float* bc0 = (const float*)d_in[6];
  const float* Wg1 = (const float*)d_in[7];
  const float* bg1 = (const float*)d_in[8];
  const float* Wc1 = (const float*)d_in[9];
  const float* bc1 = (const float*)d_in[10];
  float* out = (float*)d_out;

  hipMemsetAsync(d_ws, 0, 256, stream);  // zero barrier state
  dcgru<<<GD, NTHR, 0, stream>>>(inputs, init_h, sup, Wg0, bg0, Wc0, bc0,
                                 Wg1, bg1, Wc1, bc1, out, d_ws);
}

// Round 4
// 10606.239 us; speedup vs baseline: 1.0194x; 1.0194x over previous
//
#include <hip/hip_runtime.h>
#include <math.h>

// DCGRU encoder — fused per-(layer,batch) persistent blocks, LDS-only
// intermediates, 3 work tiles. B=16 T=32 N=128 D=H=128, K=2 (M=3), L=2.
//
// R3 post-mortem: __launch_bounds__(1024,4) capped VGPRs at 64 ->
// accumulators+temps spilled to scratch: WRITE_SIZE 2.49GB / FETCH 3.0GB
// = 5.6GB at 523GB/s = the whole 10.8ms runtime. Same structure, two fixes:
//  1) __launch_bounds__(1024) only -> 128 combined VGPR+AGPR per wave
//     (16-wave block, 1 block/CU due to LDS).
//  2) Third 32KB LDS tile (160KB total) removes the Chebyshev register
//     capture and staging array: each hop reads ONE tile, writes the other
//     two, so x0 (xT/hT/rhT) stays intact and hop2 reads it from LDS.
// Per-stage global traffic: weight B-frags (~4.6MB/block, L2-resident),
// x reads, seqs/out writes. No intermediate leaves the CU.
// Grid: 32 blocks x 1024 thr, 33 grid barriers (layer pipeline only).

typedef __attribute__((ext_vector_type(8))) short bf16x8;
typedef __attribute__((ext_vector_type(4))) float f32x4;

namespace {
constexpr int GD = 32, NTHR = 1024;
}

__device__ __forceinline__ unsigned short f2bf(float x) {
  unsigned u = __float_as_uint(x);
  u += 0x7fff + ((u >> 16) & 1);  // RNE
  return (unsigned short)(u >> 16);
}
__device__ __forceinline__ float bf2f(unsigned hw) {
  return __uint_as_float(hw << 16);
}
__device__ __forceinline__ unsigned pk2(float a, float b) {
  return (unsigned)f2bf(a) | ((unsigned)f2bf(b) << 16);
}
// swizzled halfword index into a [128][128] bf16 LDS tile (row stride 256B)
__device__ __forceinline__ int BIdx(int r, int c) {
  return (r << 7) + (c ^ ((r & 7) << 3));
}
// swizzled word index into the [128][128] f32 h tile
__device__ __forceinline__ int HsIdx(int n, int f) {
  return (n << 7) + (f ^ (n & 31));
}

// sense-reversing grid barrier (verified across XCDs in earlier rounds)
__device__ __forceinline__ void grid_barrier(unsigned* bar) {
  __syncthreads();
  if (threadIdx.x == 0) {
    unsigned* cnt = bar;
    unsigned* gen = bar + 32;
    unsigned g = __hip_atomic_load(gen, __ATOMIC_RELAXED, __HIP_MEMORY_SCOPE_AGENT);
    unsigned a = __hip_atomic_fetch_add(cnt, 1u, __ATOMIC_ACQ_REL, __HIP_MEMORY_SCOPE_AGENT);
    if (a == (unsigned)(GD - 1)) {
      __hip_atomic_store(cnt, 0u, __ATOMIC_RELAXED, __HIP_MEMORY_SCOPE_AGENT);
      __hip_atomic_fetch_add(gen, 1u, __ATOMIC_ACQ_REL, __HIP_MEMORY_SCOPE_AGENT);
    } else {
      while (__hip_atomic_load(gen, __ATOMIC_ACQUIRE, __HIP_MEMORY_SCOPE_AGENT) == g) {
        __builtin_amdgcn_s_sleep(1);
      }
    }
  }
  __syncthreads();
}

// One diffusion hop (16 waves, 32m x 32f tiles): out = S @ Bt (Bt f-major
// [f][n] in LDS). Optional Chebyshev out = 2*out - CtT[f][m] (read from the
// intact source tile). Optional f-major write (next hop's B-operand).
// Row-major write always (weight-GEMM A-chunk). Reads and writes touch
// DIFFERENT tiles -> no intra-hop sync needed.
template <bool HASCT, bool FMAJ>
__device__ __forceinline__ void diff_hop(
    const unsigned short* __restrict__ Sb, const unsigned short* Bt,
    const unsigned short* CtT, unsigned short* fmaj, unsigned short* rmaj,
    int w, int lane, int quad, int l16) {
  const int mtg = w >> 2, ftg = w & 3;
  f32x4 acc[2][2];
#pragma unroll
  for (int mi = 0; mi < 2; ++mi)
#pragma unroll
    for (int fi = 0; fi < 2; ++fi) acc[mi][fi] = (f32x4){0.f, 0.f, 0.f, 0.f};
#pragma unroll
  for (int ks = 0; ks < 4; ++ks) {
    bf16x8 a[2], bb[2];
#pragma unroll
    for (int mi = 0; mi < 2; ++mi)
      a[mi] = *(const bf16x8*)(Sb + (((mtg * 2 + mi) * 4 + ks) * 64 + lane) * 8);
#pragma unroll
    for (int fi = 0; fi < 2; ++fi)
      bb[fi] = *(const bf16x8*)(Bt + BIdx((ftg * 2 + fi) * 16 + l16, ks * 32 + quad * 8));
#pragma unroll
    for (int mi = 0; mi < 2; ++mi)
#pragma unroll
      for (int fi = 0; fi < 2; ++fi)
        acc[mi][fi] =
            __builtin_amdgcn_mfma_f32_16x16x32_bf16(a[mi], bb[fi], acc[mi][fi], 0, 0, 0);
  }
#pragma unroll
  for (int mi = 0; mi < 2; ++mi)
#pragma unroll
    for (int fi = 0; fi < 2; ++fi) {
      const int f = (ftg * 2 + fi) * 16 + l16;
      const int m0 = (mtg * 2 + mi) * 16 + quad * 4;
      float v0 = acc[mi][fi][0], v1 = acc[mi][fi][1];
      float v2 = acc[mi][fi][2], v3 = acc[mi][fi][3];
      if (HASCT) {
        const uint2 cv = *(const uint2*)(CtT + BIdx(f, m0));
        v0 = 2.f * v0 - bf2f(cv.x & 0xffffu);
        v1 = 2.f * v1 - bf2f(cv.x >> 16);
        v2 = 2.f * v2 - bf2f(cv.y & 0xffffu);
        v3 = 2.f * v3 - bf2f(cv.y >> 16);
      }
      if (FMAJ)
        *(uint2*)(fmaj + BIdx(f, m0)) = make_uint2(pk2(v0, v1), pk2(v2, v3));
      rmaj[BIdx(m0 + 0, f)] = f2bf(v0);
      rmaj[BIdx(m0 + 1, f)] = f2bf(v1);
      rmaj[BIdx(m0 + 2, f)] = f2bf(v2);
      rmaj[BIdx(m0 + 3, f)] = f2bf(v3);
    }
}

// A-fragment loaders (16x16x32 A-operand: lane l16 = row m, quad = k-group)
__device__ __forceinline__ bf16x8 afrag_rm(const unsigned short* T, int m, int k0) {
  return *(const bf16x8*)(T + BIdx(m, k0));
}
__device__ __forceinline__ bf16x8 afrag_G(const float* __restrict__ g, int m, int k0) {
  const float4 v0 = *(const float4*)(g + m * 128 + k0);
  const float4 v1 = *(const float4*)(g + m * 128 + k0 + 4);
  bf16x8 a;
  a[0] = (short)f2bf(v0.x); a[1] = (short)f2bf(v0.y);
  a[2] = (short)f2bf(v0.z); a[3] = (short)f2bf(v0.w);
  a[4] = (short)f2bf(v1.x); a[5] = (short)f2bf(v1.y);
  a[6] = (short)f2bf(v1.z); a[7] = (short)f2bf(v1.w);
  return a;
}
__device__ __forceinline__ bf16x8 afrag_Hs(const float* Hsp, int m, int k0) {
  bf16x8 a;
#pragma unroll
  for (int j = 0; j < 8; ++j) a[j] = (short)f2bf(Hsp[HsIdx(m, k0 + j)]);
  return a;
}

// weight-GEMM accumulate for one k-chunk c (gates: 8 o-frags = r+u halves)
__device__ __forceinline__ void gemm_gates(const bf16x8 (&af)[4],
    const unsigned short* __restrict__ WgL, int c, int ow, int lane, f32x4 (&accg)[8]) {
#pragma unroll
  for (int ks = 0; ks < 4; ++ks)
#pragma unroll
    for (int of = 0; of < 8; ++of) {
      const int ot = (of < 4) ? (ow * 4 + of) : (4 + ow * 4 + of);  // u-half -> ot 8..15
      const bf16x8 bb =
          *(const bf16x8*)(WgL + ((long)(ot * 24 + c * 4 + ks)) * 512 + (long)lane * 8);
      accg[of] = __builtin_amdgcn_mfma_f32_16x16x32_bf16(af[ks], bb, accg[of], 0, 0, 0);
    }
}
__device__ __forceinline__ void gemm_cand(const bf16x8 (&af)[4],
    const unsigned short* __restrict__ WcL, int c, int ow, int lane, f32x4 (&accc)[4]) {
#pragma unroll
  for (int ks = 0; ks < 4; ++ks)
#pragma unroll
    for (int of = 0; of < 4; ++of) {
      const int ot = ow * 4 + of;
      const bf16x8 bb =
          *(const bf16x8*)(WcL + ((long)(ot * 24 + c * 4 + ks)) * 512 + (long)lane * 8);
      accc[of] = __builtin_amdgcn_mfma_f32_16x16x32_bf16(af[ks], bb, accc[of], 0, 0, 0);
    }
}

__global__ void __launch_bounds__(NTHR) dcgru(
    const float* __restrict__ inputs, const float* __restrict__ init_h,
    const float* __restrict__ sup,
    const float* __restrict__ Wg0, const float* __restrict__ bg0,
    const float* __restrict__ Wc0, const float* __restrict__ bc0,
    const float* __restrict__ Wg1, const float* __restrict__ bg1,
    const float* __restrict__ Wc1, const float* __restrict__ bc1,
    float* __restrict__ out, void* __restrict__ wsv) {
  __shared__ float Hs[16384];           // 64 KB h state (f32, swizzled)
  __shared__ unsigned short T1[16384];  // 32 KB work tile (xT/hT/rhT: hop src)
  __shared__ unsigned short T2[16384];  // 32 KB work tile (fmaj hop output)
  __shared__ unsigned short T3[16384];  // 32 KB work tile (rmaj GEMM A-chunks)

  unsigned* bar = (unsigned*)wsv;
  float* seqs = (float*)wsv + 64;                           // [2][16][128][128]
  unsigned short* Sfr = (unsigned short*)(seqs + 524288);   // [32][8][4][64][8]
  unsigned short* Wbg = Sfr + 524288;                       // [2][16][24][64][8]
  unsigned short* Wbc = Wbg + 393216;                       // [2][8][24][64][8]

  const int tid = threadIdx.x, bid = blockIdx.x;
  const int gtid = bid * NTHR + tid, gstride = GD * NTHR;
  const int lane = tid & 63, w = tid >> 6, quad = lane >> 4, l16 = lane & 15;
  const int layer = bid >> 4, b = bid & 15;
  const int mw = w >> 1, ow = w & 1;  // GEMM tiling: wave = 16m x 64o

  // ---- prep: h -> LDS; S/W fragment pre-arrangement (bf16) ----
  for (int i = tid; i < 16384; i += NTHR)
    Hs[HsIdx(i >> 7, i & 127)] = init_h[(long)(layer * 16 + b) * 16384 + i];
  for (int idx = gtid; idx < 65536; idx += gstride) {  // S frags
    const int tt = idx >> 11, mt = (idx >> 8) & 7, ks = (idx >> 6) & 3, ln = idx & 63;
    const int m = mt * 16 + (ln & 15), k0 = ks * 32 + (ln >> 4) * 8;
    const float* src = sup + (long)tt * 16384 + m * 128 + k0;
    bf16x8 v;
#pragma unroll
    for (int j = 0; j < 8; j++) v[j] = (short)f2bf(src[j]);
    *(bf16x8*)(Sfr + (long)idx * 8) = v;
  }
  for (int idx = gtid; idx < 49152; idx += gstride) {  // Wg frags (2x16x24x64)
    const int l = idx / 24576;
    int rem = idx - l * 24576;
    const int ot = rem / 1536; rem -= ot * 1536;
    const int ks = rem >> 6, ln = rem & 63;
    const int o = ot * 16 + (ln & 15);
    const float* W = l ? Wg1 : Wg0;
    bf16x8 v;
#pragma unroll
    for (int j = 0; j < 8; j++) {
      const int kk = ks * 32 + (ln >> 4) * 8 + j;
      const int mm = kk >> 8, d = kk & 255;  // row reorder (d*3+mm) -> k
      v[j] = (short)f2bf(W[(d * 3 + mm) * 256 + o]);
    }
    *(bf16x8*)(Wbg + (long)idx * 8) = v;
  }
  for (int idx = gtid; idx < 24576; idx += gstride) {  // Wc frags (2x8x24x64)
    const int l = idx / 12288;
    int rem = idx - l * 12288;
    const int ot = rem / 1536; rem -= ot * 1536;
    const int ks = rem >> 6, ln = rem & 63;
    const int o = ot * 16 + (ln & 15);
    const float* W = l ? Wc1 : Wc0;
    bf16x8 v;
#pragma unroll
    for (int j = 0; j < 8; j++) {
      const int kk = ks * 32 + (ln >> 4) * 8 + j;
      const int mm = kk >> 8, d = kk & 255;
      v[j] = (short)f2bf(W[(d * 3 + mm) * 128 + o]);
    }
    *(bf16x8*)(Wbc + (long)idx * 8) = v;
  }
  grid_barrier(bar);

  const float* bgL = layer ? bg1 : bg0;
  const float* bcL = layer ? bc1 : bc0;
  const unsigned short* WgL = Wbg + (long)layer * 16 * 24 * 512;
  const unsigned short* WcL = Wbc + (long)layer * 8 * 24 * 512;

  // ---- main pipelined loop: stage s, layer0 does t=s, layer1 does t=s-1 ----
  for (int s = 0; s < 33; ++s) {
    const int t = layer ? (s - 1) : s;
    const bool act = layer ? (s >= 1) : (s < 32);
    if (act) {
      const float* xsrc = (layer == 0)
          ? inputs + (long)(b * 32 + t) * 16384
          : seqs + (long)(t & 1) * 262144 + (long)b * 16384;
      const unsigned short* Sb = Sfr + (long)t * 16384;
      const int m = mw * 16 + l16;

      f32x4 accg[8], accc[4];
#pragma unroll
      for (int of = 0; of < 8; ++of) accg[of] = (f32x4){0.f, 0.f, 0.f, 0.f};
#pragma unroll
      for (int of = 0; of < 4; ++of) accc[of] = (f32x4){0.f, 0.f, 0.f, 0.f};

      // ---- phase A: x | D1x | D2x (feeds both GEMMs, chunks 0/2/4) ----
      // A1: build xT -> T1
#pragma unroll
      for (int it = 0; it < 8; ++it) {
        const int f = it * 16 + w, n2 = lane << 1;
        const float v0 = xsrc[n2 * 128 + f], v1 = xsrc[(n2 + 1) * 128 + f];
        *(unsigned*)(T1 + BIdx(f, n2)) = pk2(v0, v1);
      }
      __syncthreads();
      // A2: D1x = S@T1 -> fmaj T2, rmaj T3 (T1 stays intact)
      diff_hop<false, true>(Sb, T1, nullptr, T2, T3, w, lane, quad, l16);
      __syncthreads();
      // A3: GEMM c0 (x from global) + c2 (D1x rmaj in T3)
      {
        bf16x8 af[4];
#pragma unroll
        for (int ks = 0; ks < 4; ++ks) af[ks] = afrag_G(xsrc, m, ks * 32 + quad * 8);
        gemm_gates(af, WgL, 0, ow, lane, accg);
        gemm_cand(af, WcL, 0, ow, lane, accc);
#pragma unroll
        for (int ks = 0; ks < 4; ++ks) af[ks] = afrag_rm(T3, m, ks * 32 + quad * 8);
        gemm_gates(af, WgL, 2, ow, lane, accg);
        gemm_cand(af, WcL, 2, ow, lane, accc);
      }
      __syncthreads();
      // A4: D2x = 2*S@T2 - xT(T1) -> rmaj T3
      diff_hop<true, false>(Sb, T2, T1, nullptr, T3, w, lane, quad, l16);
      __syncthreads();
      // A5: GEMM c4 (D2x in T3)  +  B1: build hT -> T1 (disjoint tiles)
      {
        bf16x8 af[4];
#pragma unroll
        for (int ks = 0; ks < 4; ++ks) af[ks] = afrag_rm(T3, m, ks * 32 + quad * 8);
        gemm_gates(af, WgL, 4, ow, lane, accg);
        gemm_cand(af, WcL, 4, ow, lane, accc);
      }
#pragma unroll
      for (int it = 0; it < 8; ++it) {
        const int f = it * 16 + w, n2 = lane << 1;
        const float v0 = Hs[HsIdx(n2, f)], v1 = Hs[HsIdx(n2 + 1, f)];
        *(unsigned*)(T1 + BIdx(f, n2)) = pk2(v0, v1);
      }
      __syncthreads();

      // ---- phase B: h | D1h | D2h (gates chunks 1/3/5) ----
      // B2: D1h = S@T1 -> fmaj T2, rmaj T3
      diff_hop<false, true>(Sb, T1, nullptr, T2, T3, w, lane, quad, l16);
      __syncthreads();
      // B3: GEMM c1 (h from Hs) + c3 (D1h in T3)
      {
        bf16x8 af[4];
#pragma unroll
        for (int ks = 0; ks < 4; ++ks) af[ks] = afrag_Hs(Hs, m, ks * 32 + quad * 8);
        gemm_gates(af, WgL, 1, ow, lane, accg);
#pragma unroll
        for (int ks = 0; ks < 4; ++ks) af[ks] = afrag_rm(T3, m, ks * 32 + quad * 8);
        gemm_gates(af, WgL, 3, ow, lane, accg);
      }
      __syncthreads();
      // B4: D2h = 2*S@T2 - hT(T1) -> rmaj T3
      diff_hop<true, false>(Sb, T2, T1, nullptr, T3, w, lane, quad, l16);
      __syncthreads();
      // B5: GEMM c5 (D2h in T3); then gates epilogue writes T1 (rhT) + T2 (rh)
      {
        bf16x8 af[4];
#pragma unroll
        for (int ks = 0; ks < 4; ++ks) af[ks] = afrag_rm(T3, m, ks * 32 + quad * 8);
        gemm_gates(af, WgL, 5, ow, lane, accg);
      }
      // gates epilogue: r -> rh (fmaj T1 + rmaj T2); u stays in accg[4..7]
#pragma unroll
      for (int of = 0; of < 4; ++of) {
        const int o = ow * 64 + of * 16 + l16;
        const float bias = bgL[o];
        const int m0 = mw * 16 + quad * 4;
        float rh[4];
#pragma unroll
        for (int r = 0; r < 4; ++r) {
          const float g = 1.f / (1.f + __expf(-(accg[of][r] + bias)));
          rh[r] = g * Hs[HsIdx(m0 + r, o)];
        }
        *(uint2*)(T1 + BIdx(o, m0)) = make_uint2(pk2(rh[0], rh[1]), pk2(rh[2], rh[3]));
        T2[BIdx(m0 + 0, o)] = f2bf(rh[0]);
        T2[BIdx(m0 + 1, o)] = f2bf(rh[1]);
        T2[BIdx(m0 + 2, o)] = f2bf(rh[2]);
        T2[BIdx(m0 + 3, o)] = f2bf(rh[3]);
      }
#pragma unroll
      for (int of = 4; of < 8; ++of) {
        const int o = 128 + ow * 64 + (of - 4) * 16 + l16;
        const float bias = bgL[o];
#pragma unroll
        for (int r = 0; r < 4; ++r)
          accg[of][r] = 1.f / (1.f + __expf(-(accg[of][r] + bias)));
      }
      __syncthreads();

      // ---- phase C: rh | D1rh | D2rh (candidate chunks 1/3/5) ----
      // C1: GEMM cand c1 (rh rmaj in T2)
      {
        bf16x8 af[4];
#pragma unroll
        for (int ks = 0; ks < 4; ++ks) af[ks] = afrag_rm(T2, m, ks * 32 + quad * 8);
        gemm_cand(af, WcL, 1, ow, lane, accc);
      }
      __syncthreads();
      // C2: D1rh = S@T1(rhT) -> fmaj T2, rmaj T3
      diff_hop<false, true>(Sb, T1, nullptr, T2, T3, w, lane, quad, l16);
      __syncthreads();
      // C3: GEMM cand c3 (D1rh in T3)
      {
        bf16x8 af[4];
#pragma unroll
        for (int ks = 0; ks < 4; ++ks) af[ks] = afrag_rm(T3, m, ks * 32 + quad * 8);
        gemm_cand(af, WcL, 3, ow, lane, accc);
      }
      __syncthreads();
      // C4: D2rh = 2*S@T2 - rhT(T1) -> rmaj T3
      diff_hop<true, false>(Sb, T2, T1, nullptr, T3, w, lane, quad, l16);
      __syncthreads();
      // C5: GEMM cand c5 (D2rh in T3); final epilogue
      {
        bf16x8 af[4];
#pragma unroll
        for (int ks = 0; ks < 4; ++ks) af[ks] = afrag_rm(T3, m, ks * 32 + quad * 8);
        gemm_cand(af, WcL, 5, ow, lane, accc);
      }
      // final epilogue: c = tanh(acc_c + bc); h' = u*h + (1-u)*c
#pragma unroll
      for (int of = 0; of < 4; ++of) {
        const int o = ow * 64 + of * 16 + l16;
        const float bias = bcL[o];
#pragma unroll
        for (int r = 0; r < 4; ++r) {
          const int mm = mw * 16 + quad * 4 + r;
          const float cv = tanhf(accc[of][r] + bias);
          const float uv = accg[4 + of][r];
          const float hv = Hs[HsIdx(mm, o)];
          const float hn = uv * hv + (1.f - uv) * cv;
          Hs[HsIdx(mm, o)] = hn;
          const long base = (long)(b * 128 + mm) * 128 + o;
          if (layer == 0) {
            seqs[(long)(s & 1) * 262144 + base] = hn;
            if (t == 31) out[base] = hn;
          } else {
            out[524288 + (long)t * 262144 + base] = hn;
            if (t == 31) out[262144 + base] = hn;
          }
        }
      }
    }  // act
    grid_barrier(bar);
  }
}

extern "C" void kernel_launch(void* const* d_in, const int* in_sizes, int n_in,
                              void* d_out, int out_size, void* d_ws, size_t ws_size,
                              hipStream_t stream) {
  const float* inputs = (const float*)d_in[0];
  const float* init_h = (const float*)d_in[1];
  const float* sup    = (const float*)d_in[2];
  const float* Wg0 = (const float*)d_in[3];
  const float* bg0 = (const float*)d_in[4];
  const float* Wc0 = (const float*)d_in[5];
  const float* bc0 = (const float*)d_in[6];
  const float* Wg1 = (const float*)d_in[7];
  const float* bg1 = (const float*)d_in[8];
  const float* Wc1 = (const float*)d_in[9];
  const float* bc1 = (const float*)d_in[10];
  float* out = (float*)d_out;

  hipMemsetAsync(d_ws, 0, 256, stream);  // zero barrier state
  dcgru<<<GD, NTHR, 0, stream>>>(inputs, init_h, sup, Wg0, bg0, Wc0, bc0,
                                 Wg1, bg1, Wc1, bc1, out, d_ws);
}

// Round 6
// 7217.387 us; speedup vs baseline: 1.4981x; 1.4695x over previous
//
#include <hip/hip_runtime.h>
#include <math.h>

// DCGRU encoder — fused per-(layer,batch) persistent blocks, LDS-only
// intermediates, 3 work tiles. B=16 T=32 N=128 D=H=128, K=2 (M=3), L=2.
//
// R4 post-mortem: 1024-thr block = 16 waves = 4 waves/EU minimum -> hard
// 128-reg/wave unified budget; 48 accumulator regs + transients spilled
// (WRITE 2.49GB/FETCH 2.96GB scratch traffic = the entire 10.6ms).
// Fix: 512-thr block (8 waves, 2 waves/EU) -> 256 regs/wave. Retiled:
//   diffusion: 8 waves x (32m x 64f), acc[2][4]
//   gates GEMM: wave (mw=w>>1, ow=w&1) = 32m x (64r+64u), accg[2][8]
//   cand  GEMM: same wave tile 32m x 64c, accc[2][4]
// Per-accumulator MFMA order unchanged -> bit-identical numerics to the
// passing R2 kernel. No intermediate leaves the CU (Hs + 3 LDS tiles).
// Grid: 32 blocks x 512 thr, 160KB LDS, 33 grid barriers (layer pipeline).

typedef __attribute__((ext_vector_type(8))) short bf16x8;
typedef __attribute__((ext_vector_type(4))) float f32x4;

namespace {
constexpr int GD = 32, NTHR = 512;
}

__device__ __forceinline__ unsigned short f2bf(float x) {
  unsigned u = __float_as_uint(x);
  u += 0x7fff + ((u >> 16) & 1);  // RNE
  return (unsigned short)(u >> 16);
}
__device__ __forceinline__ float bf2f(unsigned hw) {
  return __uint_as_float(hw << 16);
}
__device__ __forceinline__ unsigned pk2(float a, float b) {
  return (unsigned)f2bf(a) | ((unsigned)f2bf(b) << 16);
}
// swizzled halfword index into a [128][128] bf16 LDS tile (row stride 256B)
__device__ __forceinline__ int BIdx(int r, int c) {
  return (r << 7) + (c ^ ((r & 7) << 3));
}
// swizzled word index into the [128][128] f32 h tile
__device__ __forceinline__ int HsIdx(int n, int f) {
  return (n << 7) + (f ^ (n & 31));
}

// sense-reversing grid barrier (verified across XCDs in earlier rounds)
__device__ __forceinline__ void grid_barrier(unsigned* bar) {
  __syncthreads();
  if (threadIdx.x == 0) {
    unsigned* cnt = bar;
    unsigned* gen = bar + 32;
    unsigned g = __hip_atomic_load(gen, __ATOMIC_RELAXED, __HIP_MEMORY_SCOPE_AGENT);
    unsigned a = __hip_atomic_fetch_add(cnt, 1u, __ATOMIC_ACQ_REL, __HIP_MEMORY_SCOPE_AGENT);
    if (a == (unsigned)(GD - 1)) {
      __hip_atomic_store(cnt, 0u, __ATOMIC_RELAXED, __HIP_MEMORY_SCOPE_AGENT);
      __hip_atomic_fetch_add(gen, 1u, __ATOMIC_ACQ_REL, __HIP_MEMORY_SCOPE_AGENT);
    } else {
      while (__hip_atomic_load(gen, __ATOMIC_ACQUIRE, __HIP_MEMORY_SCOPE_AGENT) == g) {
        __builtin_amdgcn_s_sleep(1);
      }
    }
  }
  __syncthreads();
}

// One diffusion hop (8 waves, 32m x 64f tiles): out = S @ Bt (Bt f-major
// [f][n] in LDS). Optional Chebyshev out = 2*out - CtT[f][m] (read from the
// intact source tile). Optional f-major write (next hop's B-operand).
// Row-major write always (weight-GEMM A-chunk). Reads and writes touch
// DIFFERENT tiles -> no intra-hop sync needed.
template <bool HASCT, bool FMAJ>
__device__ __forceinline__ void diff_hop(
    const unsigned short* __restrict__ Sb, const unsigned short* Bt,
    const unsigned short* CtT, unsigned short* fmaj, unsigned short* rmaj,
    int w, int lane, int quad, int l16) {
  const int mtg = w >> 1, ftg = w & 1;
  f32x4 acc[2][4];
#pragma unroll
  for (int mi = 0; mi < 2; ++mi)
#pragma unroll
    for (int fi = 0; fi < 4; ++fi) acc[mi][fi] = (f32x4){0.f, 0.f, 0.f, 0.f};
#pragma unroll
  for (int ks = 0; ks < 4; ++ks) {
    bf16x8 a[2], bb[4];
#pragma unroll
    for (int mi = 0; mi < 2; ++mi)
      a[mi] = *(const bf16x8*)(Sb + (((mtg * 2 + mi) * 4 + ks) * 64 + lane) * 8);
#pragma unroll
    for (int fi = 0; fi < 4; ++fi)
      bb[fi] = *(const bf16x8*)(Bt + BIdx((ftg * 4 + fi) * 16 + l16, ks * 32 + quad * 8));
#pragma unroll
    for (int mi = 0; mi < 2; ++mi)
#pragma unroll
      for (int fi = 0; fi < 4; ++fi)
        acc[mi][fi] =
            __builtin_amdgcn_mfma_f32_16x16x32_bf16(a[mi], bb[fi], acc[mi][fi], 0, 0, 0);
  }
#pragma unroll
  for (int mi = 0; mi < 2; ++mi)
#pragma unroll
    for (int fi = 0; fi < 4; ++fi) {
      const int f = (ftg * 4 + fi) * 16 + l16;
      const int m0 = (mtg * 2 + mi) * 16 + quad * 4;
      float v0 = acc[mi][fi][0], v1 = acc[mi][fi][1];
      float v2 = acc[mi][fi][2], v3 = acc[mi][fi][3];
      if (HASCT) {
        const uint2 cv = *(const uint2*)(CtT + BIdx(f, m0));
        v0 = 2.f * v0 - bf2f(cv.x & 0xffffu);
        v1 = 2.f * v1 - bf2f(cv.x >> 16);
        v2 = 2.f * v2 - bf2f(cv.y & 0xffffu);
        v3 = 2.f * v3 - bf2f(cv.y >> 16);
      }
      if (FMAJ)
        *(uint2*)(fmaj + BIdx(f, m0)) = make_uint2(pk2(v0, v1), pk2(v2, v3));
      rmaj[BIdx(m0 + 0, f)] = f2bf(v0);
      rmaj[BIdx(m0 + 1, f)] = f2bf(v1);
      rmaj[BIdx(m0 + 2, f)] = f2bf(v2);
      rmaj[BIdx(m0 + 3, f)] = f2bf(v3);
    }
}

// A-fragment loaders (16x16x32 A-operand: lane l16 = row m, quad = k-group)
__device__ __forceinline__ bf16x8 afrag_rm(const unsigned short* T, int m, int k0) {
  return *(const bf16x8*)(T + BIdx(m, k0));
}
__device__ __forceinline__ bf16x8 afrag_G(const float* __restrict__ g, int m, int k0) {
  const float4 v0 = *(const float4*)(g + m * 128 + k0);
  const float4 v1 = *(const float4*)(g + m * 128 + k0 + 4);
  bf16x8 a;
  a[0] = (short)f2bf(v0.x); a[1] = (short)f2bf(v0.y);
  a[2] = (short)f2bf(v0.z); a[3] = (short)f2bf(v0.w);
  a[4] = (short)f2bf(v1.x); a[5] = (short)f2bf(v1.y);
  a[6] = (short)f2bf(v1.z); a[7] = (short)f2bf(v1.w);
  return a;
}
__device__ __forceinline__ bf16x8 afrag_Hs(const float* Hsp, int m, int k0) {
  bf16x8 a;
#pragma unroll
  for (int j = 0; j < 8; ++j) a[j] = (short)f2bf(Hsp[HsIdx(m, k0 + j)]);
  return a;
}

// weight-GEMM accumulate for one k-chunk c. af[mi][ks] prepared by caller.
// gates: 8 o-frags (r half of<4, u half of>=4), both m-frags share bb.
__device__ __forceinline__ void gemm_gates(const bf16x8 (&af)[2][4],
    const unsigned short* __restrict__ WgL, int c, int ow, int lane,
    f32x4 (&accg)[2][8]) {
#pragma unroll
  for (int ks = 0; ks < 4; ++ks)
#pragma unroll
    for (int of = 0; of < 8; ++of) {
      const int ot = (of < 4) ? (ow * 4 + of) : (4 + ow * 4 + of);  // u-half -> ot 8..15
      const bf16x8 bb =
          *(const bf16x8*)(WgL + ((long)(ot * 24 + c * 4 + ks)) * 512 + (long)lane * 8);
      accg[0][of] = __builtin_amdgcn_mfma_f32_16x16x32_bf16(af[0][ks], bb, accg[0][of], 0, 0, 0);
      accg[1][of] = __builtin_amdgcn_mfma_f32_16x16x32_bf16(af[1][ks], bb, accg[1][of], 0, 0, 0);
    }
}
__device__ __forceinline__ void gemm_cand(const bf16x8 (&af)[2][4],
    const unsigned short* __restrict__ WcL, int c, int ow, int lane,
    f32x4 (&accc)[2][4]) {
#pragma unroll
  for (int ks = 0; ks < 4; ++ks)
#pragma unroll
    for (int of = 0; of < 4; ++of) {
      const int ot = ow * 4 + of;
      const bf16x8 bb =
          *(const bf16x8*)(WcL + ((long)(ot * 24 + c * 4 + ks)) * 512 + (long)lane * 8);
      accc[0][of] = __builtin_amdgcn_mfma_f32_16x16x32_bf16(af[0][ks], bb, accc[0][of], 0, 0, 0);
      accc[1][of] = __builtin_amdgcn_mfma_f32_16x16x32_bf16(af[1][ks], bb, accc[1][of], 0, 0, 0);
    }
}

__global__ void __launch_bounds__(NTHR, 2) dcgru(
    const float* __restrict__ inputs, const float* __restrict__ init_h,
    const float* __restrict__ sup,
    const float* __restrict__ Wg0, const float* __restrict__ bg0,
    const float* __restrict__ Wc0, const float* __restrict__ bc0,
    const float* __restrict__ Wg1, const float* __restrict__ bg1,
    const float* __restrict__ Wc1, const float* __restrict__ bc1,
    float* __restrict__ out, void* __restrict__ wsv) {
  __shared__ float Hs[16384];           // 64 KB h state (f32, swizzled)
  __shared__ unsigned short T1[16384];  // 32 KB work tile (xT/hT/rhT: hop src)
  __shared__ unsigned short T2[16384];  // 32 KB work tile (fmaj hop output)
  __shared__ unsigned short T3[16384];  // 32 KB work tile (rmaj GEMM A-chunks)

  unsigned* bar = (unsigned*)wsv;
  float* seqs = (float*)wsv + 64;                           // [2][16][128][128]
  unsigned short* Sfr = (unsigned short*)(seqs + 524288);   // [32][8][4][64][8]
  unsigned short* Wbg = Sfr + 524288;                       // [2][16][24][64][8]
  unsigned short* Wbc = Wbg + 393216;                       // [2][8][24][64][8]

  const int tid = threadIdx.x, bid = blockIdx.x;
  const int gtid = bid * NTHR + tid, gstride = GD * NTHR;
  const int lane = tid & 63, w = tid >> 6, quad = lane >> 4, l16 = lane & 15;
  const int layer = bid >> 4, b = bid & 15;
  const int mw = w >> 1, ow = w & 1;  // GEMM tiling: wave = 32m x 64o

  // ---- prep: h -> LDS; S/W fragment pre-arrangement (bf16) ----
  for (int i = tid; i < 16384; i += NTHR)
    Hs[HsIdx(i >> 7, i & 127)] = init_h[(long)(layer * 16 + b) * 16384 + i];
  for (int idx = gtid; idx < 65536; idx += gstride) {  // S frags
    const int tt = idx >> 11, mt = (idx >> 8) & 7, ks = (idx >> 6) & 3, ln = idx & 63;
    const int m = mt * 16 + (ln & 15), k0 = ks * 32 + (ln >> 4) * 8;
    const float* src = sup + (long)tt * 16384 + m * 128 + k0;
    bf16x8 v;
#pragma unroll
    for (int j = 0; j < 8; j++) v[j] = (short)f2bf(src[j]);
    *(bf16x8*)(Sfr + (long)idx * 8) = v;
  }
  for (int idx = gtid; idx < 49152; idx += gstride) {  // Wg frags (2x16x24x64)
    const int l = idx / 24576;
    int rem = idx - l * 24576;
    const int ot = rem / 1536; rem -= ot * 1536;
    const int ks = rem >> 6, ln = rem & 63;
    const int o = ot * 16 + (ln & 15);
    const float* W = l ? Wg1 : Wg0;
    bf16x8 v;
#pragma unroll
    for (int j = 0; j < 8; j++) {
      const int kk = ks * 32 + (ln >> 4) * 8 + j;
      const int mm = kk >> 8, d = kk & 255;  // row reorder (d*3+mm) -> k
      v[j] = (short)f2bf(W[(d * 3 + mm) * 256 + o]);
    }
    *(bf16x8*)(Wbg + (long)idx * 8) = v;
  }
  for (int idx = gtid; idx < 24576; idx += gstride) {  // Wc frags (2x8x24x64)
    const int l = idx / 12288;
    int rem = idx - l * 12288;
    const int ot = rem / 1536; rem -= ot * 1536;
    const int ks = rem >> 6, ln = rem & 63;
    const int o = ot * 16 + (ln & 15);
    const float* W = l ? Wc1 : Wc0;
    bf16x8 v;
#pragma unroll
    for (int j = 0; j < 8; j++) {
      const int kk = ks * 32 + (ln >> 4) * 8 + j;
      const int mm = kk >> 8, d = kk & 255;
      v[j] = (short)f2bf(W[(d * 3 + mm) * 128 + o]);
    }
    *(bf16x8*)(Wbc + (long)idx * 8) = v;
  }
  grid_barrier(bar);

  const float* bgL = layer ? bg1 : bg0;
  const float* bcL = layer ? bc1 : bc0;
  const unsigned short* WgL = Wbg + (long)layer * 16 * 24 * 512;
  const unsigned short* WcL = Wbc + (long)layer * 8 * 24 * 512;

  // ---- main pipelined loop: stage s, layer0 does t=s, layer1 does t=s-1 ----
  for (int s = 0; s < 33; ++s) {
    const int t = layer ? (s - 1) : s;
    const bool act = layer ? (s >= 1) : (s < 32);
    if (act) {
      const float* xsrc = (layer == 0)
          ? inputs + (long)(b * 32 + t) * 16384
          : seqs + (long)(t & 1) * 262144 + (long)b * 16384;
      const unsigned short* Sb = Sfr + (long)t * 16384;

      f32x4 accg[2][8], accc[2][4];
#pragma unroll
      for (int mi = 0; mi < 2; ++mi) {
#pragma unroll
        for (int of = 0; of < 8; ++of) accg[mi][of] = (f32x4){0.f, 0.f, 0.f, 0.f};
#pragma unroll
        for (int of = 0; of < 4; ++of) accc[mi][of] = (f32x4){0.f, 0.f, 0.f, 0.f};
      }
      bf16x8 af[2][4];

      // ---- phase A: x | D1x | D2x (feeds both GEMMs, chunks 0/2/4) ----
      // A1: build xT -> T1
#pragma unroll
      for (int it = 0; it < 16; ++it) {
        const int f = it * 8 + w, n2 = lane << 1;
        const float v0 = xsrc[n2 * 128 + f], v1 = xsrc[(n2 + 1) * 128 + f];
        *(unsigned*)(T1 + BIdx(f, n2)) = pk2(v0, v1);
      }
      __syncthreads();
      // A2: D1x = S@T1 -> fmaj T2, rmaj T3 (T1 stays intact)
      diff_hop<false, true>(Sb, T1, nullptr, T2, T3, w, lane, quad, l16);
      __syncthreads();
      // A3: GEMM c0 (x from global) + c2 (D1x rmaj in T3)
#pragma unroll
      for (int mi = 0; mi < 2; ++mi)
#pragma unroll
        for (int ks = 0; ks < 4; ++ks)
          af[mi][ks] = afrag_G(xsrc, mw * 32 + mi * 16 + l16, ks * 32 + quad * 8);
      gemm_gates(af, WgL, 0, ow, lane, accg);
      gemm_cand(af, WcL, 0, ow, lane, accc);
#pragma unroll
      for (int mi = 0; mi < 2; ++mi)
#pragma unroll
        for (int ks = 0; ks < 4; ++ks)
          af[mi][ks] = afrag_rm(T3, mw * 32 + mi * 16 + l16, ks * 32 + quad * 8);
      gemm_gates(af, WgL, 2, ow, lane, accg);
      gemm_cand(af, WcL, 2, ow, lane, accc);
      __syncthreads();
      // A4: D2x = 2*S@T2 - xT(T1) -> rmaj T3
      diff_hop<true, false>(Sb, T2, T1, nullptr, T3, w, lane, quad, l16);
      __syncthreads();
      // A5: GEMM c4 (D2x in T3)  +  B1: build hT -> T1 (disjoint tiles)
#pragma unroll
      for (int mi = 0; mi < 2; ++mi)
#pragma unroll
        for (int ks = 0; ks < 4; ++ks)
          af[mi][ks] = afrag_rm(T3, mw * 32 + mi * 16 + l16, ks * 32 + quad * 8);
      gemm_gates(af, WgL, 4, ow, lane, accg);
      gemm_cand(af, WcL, 4, ow, lane, accc);
#pragma unroll
      for (int it = 0; it < 16; ++it) {
        const int f = it * 8 + w, n2 = lane << 1;
        const float v0 = Hs[HsIdx(n2, f)], v1 = Hs[HsIdx(n2 + 1, f)];
        *(unsigned*)(T1 + BIdx(f, n2)) = pk2(v0, v1);
      }
      __syncthreads();

      // ---- phase B: h | D1h | D2h (gates chunks 1/3/5) ----
      // B2: D1h = S@T1 -> fmaj T2, rmaj T3
      diff_hop<false, true>(Sb, T1, nullptr, T2, T3, w, lane, quad, l16);
      __syncthreads();
      // B3: GEMM c1 (h from Hs) + c3 (D1h in T3)
#pragma unroll
      for (int mi = 0; mi < 2; ++mi)
#pragma unroll
        for (int ks = 0; ks < 4; ++ks)
          af[mi][ks] = afrag_Hs(Hs, mw * 32 + mi * 16 + l16, ks * 32 + quad * 8);
      gemm_gates(af, WgL, 1, ow, lane, accg);
#pragma unroll
      for (int mi = 0; mi < 2; ++mi)
#pragma unroll
        for (int ks = 0; ks < 4; ++ks)
          af[mi][ks] = afrag_rm(T3, mw * 32 + mi * 16 + l16, ks * 32 + quad * 8);
      gemm_gates(af, WgL, 3, ow, lane, accg);
      __syncthreads();
      // B4: D2h = 2*S@T2 - hT(T1) -> rmaj T3
      diff_hop<true, false>(Sb, T2, T1, nullptr, T3, w, lane, quad, l16);
      __syncthreads();
      // B5: GEMM c5 (D2h in T3); then gates epilogue writes T1 (rhT) + T2 (rh)
#pragma unroll
      for (int mi = 0; mi < 2; ++mi)
#pragma unroll
        for (int ks = 0; ks < 4; ++ks)
          af[mi][ks] = afrag_rm(T3, mw * 32 + mi * 16 + l16, ks * 32 + quad * 8);
      gemm_gates(af, WgL, 5, ow, lane, accg);
      // gates epilogue: r -> rh (fmaj T1 + rmaj T2); u stays in accg[*][4..7]
#pragma unroll
      for (int mi = 0; mi < 2; ++mi) {
#pragma unroll
        for (int of = 0; of < 4; ++of) {
          const int o = ow * 64 + of * 16 + l16;
          const float bias = bgL[o];
          const int m0 = mw * 32 + mi * 16 + quad * 4;
          float rh[4];
#pragma unroll
          for (int r = 0; r < 4; ++r) {
            const float g = 1.f / (1.f + __expf(-(accg[mi][of][r] + bias)));
            rh[r] = g * Hs[HsIdx(m0 + r, o)];
          }
          *(uint2*)(T1 + BIdx(o, m0)) = make_uint2(pk2(rh[0], rh[1]), pk2(rh[2], rh[3]));
          T2[BIdx(m0 + 0, o)] = f2bf(rh[0]);
          T2[BIdx(m0 + 1, o)] = f2bf(rh[1]);
          T2[BIdx(m0 + 2, o)] = f2bf(rh[2]);
          T2[BIdx(m0 + 3, o)] = f2bf(rh[3]);
        }
#pragma unroll
        for (int of = 4; of < 8; ++of) {
          const int o = 128 + ow * 64 + (of - 4) * 16 + l16;
          const float bias = bgL[o];
#pragma unroll
          for (int r = 0; r < 4; ++r)
            accg[mi][of][r] = 1.f / (1.f + __expf(-(accg[mi][of][r] + bias)));
        }
      }
      __syncthreads();

      // ---- phase C: rh | D1rh | D2rh (candidate chunks 1/3/5) ----
      // C1: GEMM cand c1 (rh rmaj in T2)
#pragma unroll
      for (int mi = 0; mi < 2; ++mi)
#pragma unroll
        for (int ks = 0; ks < 4; ++ks)
          af[mi][ks] = afrag_rm(T2, mw * 32 + mi * 16 + l16, ks * 32 + quad * 8);
      gemm_cand(af, WcL, 1, ow, lane, accc);
      __syncthreads();
      // C2: D1rh = S@T1(rhT) -> fmaj T2, rmaj T3
      diff_hop<false, true>(Sb, T1, nullptr, T2, T3, w, lane, quad, l16);
      __syncthreads();
      // C3: GEMM cand c3 (D1rh in T3)
#pragma unroll
      for (int mi = 0; mi < 2; ++mi)
#pragma unroll
        for (int ks = 0; ks < 4; ++ks)
          af[mi][ks] = afrag_rm(T3, mw * 32 + mi * 16 + l16, ks * 32 + quad * 8);
      gemm_cand(af, WcL, 3, ow, lane, accc);
      __syncthreads();
      // C4: D2rh = 2*S@T2 - rhT(T1) -> rmaj T3
      diff_hop<true, false>(Sb, T2, T1, nullptr, T3, w, lane, quad, l16);
      __syncthreads();
      // C5: GEMM cand c5 (D2rh in T3); final epilogue
#pragma unroll
      for (int mi = 0; mi < 2; ++mi)
#pragma unroll
        for (int ks = 0; ks < 4; ++ks)
          af[mi][ks] = afrag_rm(T3, mw * 32 + mi * 16 + l16, ks * 32 + quad * 8);
      gemm_cand(af, WcL, 5, ow, lane, accc);
      // final epilogue: c = tanh(acc_c + bc); h' = u*h + (1-u)*c
#pragma unroll
      for (int mi = 0; mi < 2; ++mi)
#pragma unroll
        for (int of = 0; of < 4; ++of) {
          const int o = ow * 64 + of * 16 + l16;
          const float bias = bcL[o];
#pragma unroll
          for (int r = 0; r < 4; ++r) {
            const int mm = mw * 32 + mi * 16 + quad * 4 + r;
            const float cv = tanhf(accc[mi][of][r] + bias);
            const float uv = accg[mi][4 + of][r];
            const float hv = Hs[HsIdx(mm, o)];
            const float hn = uv * hv + (1.f - uv) * cv;
            Hs[HsIdx(mm, o)] = hn;
            const long base = (long)(b * 128 + mm) * 128 + o;
            if (layer == 0) {
              seqs[(long)(s & 1) * 262144 + base] = hn;
              if (t == 31) out[base] = hn;
            } else {
              out[524288 + (long)t * 262144 + base] = hn;
              if (t == 31) out[262144 + base] = hn;
            }
          }
        }
    }  // act
    grid_barrier(bar);
  }
}

extern "C" void kernel_launch(void* const* d_in, const int* in_sizes, int n_in,
                              void* d_out, int out_size, void* d_ws, size_t ws_size,
                              hipStream_t stream) {
  const float* inputs = (const float*)d_in[0];
  const float* init_h = (const float*)d_in[1];
  const float* sup    = (const float*)d_in[2];
  const float* Wg0 = (const float*)d_in[3];
  const float* bg0 = (const float*)d_in[4];
  const float* Wc0 = (const float*)d_in[5];
  const float* bc0 = (const float*)d_in[6];
  const float* Wg1 = (const float*)d_in[7];
  const float* bg1 = (const float*)d_in[8];
  const float* Wc1 = (const float*)d_in[9];
  const float* bc1 = (const float*)d_in[10];
  float* out = (float*)d_out;

  hipMemsetAsync(d_ws, 0, 256, stream);  // zero barrier state
  dcgru<<<GD, NTHR, 0, stream>>>(inputs, init_h, sup, Wg0, bg0, Wc0, bc0,
                                 Wg1, bg1, Wc1, bc1, out, d_ws);
}